// Round 1
// baseline (1839.654 us; speedup 1.0000x reference)
//
#include <hip/hip_runtime.h>
#include <stdint.h>

typedef float    f32x4  __attribute__((ext_vector_type(4)));
typedef __bf16   bf16x8 __attribute__((ext_vector_type(8)));
typedef uint16_t u16x8  __attribute__((ext_vector_type(8)));
typedef uint16_t u16x4  __attribute__((ext_vector_type(4)));

static __device__ __forceinline__ f32x4 mfma_bf16(bf16x8 a, bf16x8 b, f32x4 c) {
  return __builtin_amdgcn_mfma_f32_16x16x32_bf16(a, b, c, 0, 0, 0);
}

// fp32 -> bf16 round-to-nearest-even (bit trick, no NaN inputs here)
static __device__ __forceinline__ uint16_t f2bf(float f) {
  uint32_t u = __builtin_bit_cast(uint32_t, f);
  u += 0x7fffu + ((u >> 16) & 1u);
  return (uint16_t)(u >> 16);
}
static __device__ __forceinline__ float bf2f(uint16_t h) {
  uint32_t u = (uint32_t)h << 16;
  return __builtin_bit_cast(float, u);
}

constexpr int Nrows = 131072;
constexpr int Dk    = 128;
constexpr int Cc    = 1024;
constexpr int BM    = 128;   // rows of x per block
constexpr int BN    = 512;   // output cols per block
constexpr int KB    = 64;    // c-dim step (contraction of GEMM2)
constexpr int NCB   = Cc / BN;                 // 2 col-blocks
constexpr int XBYTES = BM * Dk * 2;            // 32768 (per hi/lo)
constexpr int PBYTES = BM * KB * 2;            // 16384 (per hi/lo)
constexpr int LDS_BYTES = 2 * XBYTES + 2 * PBYTES + Cc * 4 + BM * 4;  // 102912

// ---------------------------------------------------------------------------
// Prep: normT_hi/lo[j][c] = bf16_split(norm[c][j])  (4 MB into d_ws)
// ---------------------------------------------------------------------------
__global__ void prep_nT(const float* __restrict__ nrm,
                        uint16_t* __restrict__ nT_hi,
                        uint16_t* __restrict__ nT_lo) {
  __shared__ float tile[64][65];
  const int jb = blockIdx.x & 15;   // 16 j-tiles
  const int cb = blockIdx.x >> 4;   // 16 c-tiles
  const int t  = threadIdx.x;       // 256
  const int r  = t >> 4;            // 0..15
  const int q  = t & 15;            // 0..15
#pragma unroll
  for (int i = 0; i < 4; ++i) {
    int row = r + i * 16;  // c within tile
    f32x4 v = *(const f32x4*)(nrm + (size_t)(cb * 64 + row) * Cc + jb * 64 + q * 4);
#pragma unroll
    for (int s = 0; s < 4; ++s) tile[row][q * 4 + s] = v[s];
  }
  __syncthreads();
#pragma unroll
  for (int i = 0; i < 4; ++i) {
    int j = r + i * 16;  // j within tile
    u16x4 hs, ls;
#pragma unroll
    for (int s = 0; s < 4; ++s) {
      float v = tile[q * 4 + s][j];
      uint16_t h = f2bf(v);
      hs[s] = h;
      ls[s] = f2bf(v - bf2f(h));
    }
    size_t o = (size_t)(jb * 64 + j) * Cc + cb * 64 + q * 4;
    *(u16x4*)(nT_hi + o) = hs;
    *(u16x4*)(nT_lo + o) = ls;
  }
}

// ---------------------------------------------------------------------------
// Fused main kernel: per block computes out[BM x BN] slice.
//   c-loop: cross = x @ cen^T (split bf16 MFMA) -> P = exp(-g*sqd) -> LDS ->
//           acc += P @ norm (split bf16 MFMA)
// ---------------------------------------------------------------------------
template <int USE_NT>
__global__ __launch_bounds__(512, 2) void nyst_main(
    const float* __restrict__ x, const float* __restrict__ cen,
    const float* __restrict__ gam, const float* __restrict__ nrm,
    const uint16_t* __restrict__ nT_hi, const uint16_t* __restrict__ nT_lo,
    float* __restrict__ out) {
  extern __shared__ char smem[];
  char*  xhiB = smem;                               // [128][128] bf16, swizzled
  char*  xloB = smem + XBYTES;
  char*  phiB = smem + 2 * XBYTES;                  // [128][64] bf16, swizzled
  char*  ploB = smem + 2 * XBYTES + PBYTES;
  float* c2s  = (float*)(smem + 2 * XBYTES + 2 * PBYTES);  // [1024]
  float* x2s  = c2s + Cc;                                  // [128]

  const int tid  = threadIdx.x;
  const int lane = tid & 63;
  const int wid  = tid >> 6;
  const int wr   = wid >> 2;  // 0..1
  const int wc   = wid & 3;   // 0..3
  const int rowb = blockIdx.x >> 1;  // N/BM = 1024 row-blocks
  const int colb = blockIdx.x & 1;   // NCB = 2

  const int l15 = lane & 15;
  const int l4  = lane >> 4;  // 0..3

  const float* xblk = x + (size_t)rowb * BM * Dk;

  // ---- stage x tile as bf16 hi/lo into swizzled LDS ----
#pragma unroll
  for (int it = 0; it < 4; ++it) {
    int ch = tid + it * 512;       // 2048 chunks of 8 elems
    int r  = ch >> 4;              // row 0..127
    int cc = ch & 15;              // 16-byte chunk within row
    const float* src = xblk + r * Dk + cc * 8;
    f32x4 v0 = *(const f32x4*)src;
    f32x4 v1 = *(const f32x4*)(src + 4);
    u16x8 hh, ll;
#pragma unroll
    for (int i = 0; i < 4; ++i) {
      uint16_t h0 = f2bf(v0[i]); hh[i]     = h0; ll[i]     = f2bf(v0[i] - bf2f(h0));
      uint16_t h1 = f2bf(v1[i]); hh[i + 4] = h1; ll[i + 4] = f2bf(v1[i] - bf2f(h1));
    }
    int off = (r * 256 + cc * 16) ^ ((r & 7) << 4);
    *(u16x8*)(xhiB + off) = hh;
    *(u16x8*)(xloB + off) = ll;
  }
  // ---- x2 per row (deterministic, one thread per row) ----
  if (tid < BM) {
    const float* src = xblk + tid * Dk;
    float ss = 0.f;
#pragma unroll 8
    for (int k = 0; k < Dk / 4; ++k) {
      f32x4 v = *(const f32x4*)(src + 4 * k);
      ss += v[0] * v[0] + v[1] * v[1] + v[2] * v[2] + v[3] * v[3];
    }
    x2s[tid] = ss;
  }
  // ---- c2 for all 1024 centers ----
#pragma unroll
  for (int rr = 0; rr < 2; ++rr) {
    int r = tid + rr * 512;
    const float* src = cen + (size_t)r * Dk;
    float ss = 0.f;
    for (int k = 0; k < Dk / 4; ++k) {
      f32x4 v = *(const f32x4*)(src + 4 * k);
      ss += v[0] * v[0] + v[1] * v[1] + v[2] * v[2] + v[3] * v[3];
    }
    c2s[r] = ss;
  }
  __syncthreads();

  const float ngam = -gam[0];

  f32x4 zero4 = {0.f, 0.f, 0.f, 0.f};
  f32x4 acc[4][8];
#pragma unroll
  for (int m = 0; m < 4; ++m)
#pragma unroll
    for (int n = 0; n < 8; ++n) acc[m][n] = zero4;

  for (int c0 = 0; c0 < Cc; c0 += KB) {
    // ================= GEMM1: cross[128][64]; this wave: rows 64*wr, cols 16*wc
    f32x4 cr[4];
#pragma unroll
    for (int m = 0; m < 4; ++m) cr[m] = zero4;

    const int ccol = c0 + 16 * wc + l15;  // center index (B's N-col)
    const float* cbase = cen + (size_t)ccol * Dk + l4 * 8;
#pragma unroll
    for (int kk = 0; kk < 4; ++kk) {
      f32x4 b0 = *(const f32x4*)(cbase + kk * 32);
      f32x4 b1 = *(const f32x4*)(cbase + kk * 32 + 4);
      u16x8 bhh, bll;
#pragma unroll
      for (int i = 0; i < 4; ++i) {
        uint16_t h0 = f2bf(b0[i]); bhh[i]     = h0; bll[i]     = f2bf(b0[i] - bf2f(h0));
        uint16_t h1 = f2bf(b1[i]); bhh[i + 4] = h1; bll[i + 4] = f2bf(b1[i] - bf2f(h1));
      }
      bf16x8 bh = __builtin_bit_cast(bf16x8, bhh);
      bf16x8 bl = __builtin_bit_cast(bf16x8, bll);
#pragma unroll
      for (int m = 0; m < 4; ++m) {
        int row = 64 * wr + 16 * m + l15;
        int off = (row * 256 + (kk * 32 + l4 * 8) * 2) ^ ((row & 7) << 4);
        bf16x8 ah = *(const bf16x8*)(xhiB + off);
        bf16x8 al = *(const bf16x8*)(xloB + off);
        cr[m] = mfma_bf16(ah, bh, cr[m]);
        cr[m] = mfma_bf16(ah, bl, cr[m]);
        cr[m] = mfma_bf16(al, bh, cr[m]);
      }
    }

    // ================= P = exp(-g*max(x2+c2-2cross,0)) -> swizzled LDS (hi/lo)
    __syncthreads();  // prev GEMM2 done reading P
    const float c2v = c2s[c0 + 16 * wc + l15];
#pragma unroll
    for (int m = 0; m < 4; ++m) {
#pragma unroll
      for (int r = 0; r < 4; ++r) {
        int row = 64 * wr + 16 * m + l4 * 4 + r;
        float s = x2s[row] + c2v - 2.f * cr[m][r];
        s = fmaxf(s, 0.f);
        float p = __expf(ngam * s);
        uint16_t hh = f2bf(p);
        uint16_t ll = f2bf(p - bf2f(hh));
        int col = 16 * wc + l15;
        int off = (row * 128 + col * 2) ^ ((row & 7) << 4);
        *(uint16_t*)(phiB + off) = hh;
        *(uint16_t*)(ploB + off) = ll;
      }
    }
    __syncthreads();

    // ================= GEMM2: acc[64x128 per wave] += P @ norm
#pragma unroll
    for (int kk = 0; kk < 2; ++kk) {
      bf16x8 pah[4], pal[4];
#pragma unroll
      for (int m = 0; m < 4; ++m) {
        int row = 64 * wr + 16 * m + l15;
        int off = (row * 128 + (kk * 32 + l4 * 8) * 2) ^ ((row & 7) << 4);
        pah[m] = *(const bf16x8*)(phiB + off);
        pal[m] = *(const bf16x8*)(ploB + off);
      }
#pragma unroll
      for (int n = 0; n < 8; ++n) {
        int j    = colb * BN + wc * 128 + 16 * n + l15;  // output col (B's N)
        int krow = c0 + kk * 32 + l4 * 8;                // contraction row
        bf16x8 bh, bl;
        if (USE_NT) {
          size_t o = (size_t)j * Cc + krow;
          bh = *(const bf16x8*)(nT_hi + o);
          bl = *(const bf16x8*)(nT_lo + o);
        } else {
          u16x8 th, tl;
#pragma unroll
          for (int i = 0; i < 8; ++i) {
            float v = nrm[(size_t)(krow + i) * Cc + j];
            uint16_t h = f2bf(v);
            th[i] = h;
            tl[i] = f2bf(v - bf2f(h));
          }
          bh = __builtin_bit_cast(bf16x8, th);
          bl = __builtin_bit_cast(bf16x8, tl);
        }
#pragma unroll
        for (int m = 0; m < 4; ++m) {
          acc[m][n] = mfma_bf16(pah[m], bh, acc[m][n]);
          acc[m][n] = mfma_bf16(pah[m], bl, acc[m][n]);
          acc[m][n] = mfma_bf16(pal[m], bh, acc[m][n]);
        }
      }
    }
  }

  // ================= epilogue: C-frag layout col=lane&15, row=(lane>>4)*4+reg
#pragma unroll
  for (int m = 0; m < 4; ++m) {
#pragma unroll
    for (int n = 0; n < 8; ++n) {
#pragma unroll
      for (int r = 0; r < 4; ++r) {
        int row = 64 * wr + 16 * m + l4 * 4 + r;
        int col = colb * BN + wc * 128 + 16 * n + l15;
        out[(size_t)(rowb * BM + row) * Cc + col] = acc[m][n][r];
      }
    }
  }
}

// ---------------------------------------------------------------------------
extern "C" void kernel_launch(void* const* d_in, const int* in_sizes, int n_in,
                              void* d_out, int out_size, void* d_ws, size_t ws_size,
                              hipStream_t stream) {
  const float* x   = (const float*)d_in[0];  // [131072,128]
  const float* cen = (const float*)d_in[1];  // [1024,128]
  const float* gam = (const float*)d_in[2];  // [1]
  const float* nrm = (const float*)d_in[3];  // [1024,1024]
  float* out = (float*)d_out;

  const size_t ntBytes = (size_t)2 * Cc * Cc * sizeof(uint16_t);  // 4 MB
  const int grid = (Nrows / BM) * NCB;  // 2048

  if (ws_size >= ntBytes) {
    uint16_t* nT_hi = (uint16_t*)d_ws;
    uint16_t* nT_lo = nT_hi + (size_t)Cc * Cc;
    prep_nT<<<256, 256, 0, stream>>>(nrm, nT_hi, nT_lo);
    nyst_main<1><<<grid, 512, LDS_BYTES, stream>>>(x, cen, gam, nrm, nT_hi, nT_lo, out);
  } else {
    nyst_main<0><<<grid, 512, LDS_BYTES, stream>>>(x, cen, gam, nrm, nullptr, nullptr, out);
  }
}